// Round 8
// baseline (141.251 us; speedup 1.0000x reference)
//
#include <hip/hip_runtime.h>
#include <math.h>

#define BQ   4
#define QN   256
#define KN   1024
#define DIN  256     // Q_SIZE == K_SIZE == V_SIZE
#define HD   128     // H

// C2 = 2*log2(e): exp2(C2*x) = e^{2x}
#define C2F   2.8853900817779268f
#define NL2E  (-2.8853900817779268f)

// ---------------------------------------------------------------------------
// Kernel 1: projections as tiled GEMM, outputs in EXP2 DOMAIN:
//   Eq  [b*QN+q][h]    = exp2(C2*qp)                   (row-major)
//   EkT4[b][h/4][k][4] = exp2(C2*kp)  (4 consecutive h per float4 -> score
//                                      reads 1 dwordx4 per 4 h, k-coalesced)
// 16-row x 128-h blocks -> 320 blocks.  Thread = 2 rows x 4 h = 8 acc.
// ---------------------------------------------------------------------------
__global__ __launch_bounds__(256, 2) void proj_kernel(const float* __restrict__ queries,
                                                      const float* __restrict__ keys,
                                                      const float* __restrict__ W_q,
                                                      const float* __restrict__ W_k,
                                                      float* __restrict__ Eq,
                                                      float* __restrict__ EkT4) {
    __shared__ float xT[32][18];    // [k][row], 16 rows + pad
    __shared__ float WT[32][136];   // [k][h]

    const int t = threadIdx.x;
    const int row0 = blockIdx.x * 16;
    const bool is_q = row0 < BQ * QN;
    const float* x = is_q ? queries : keys;
    const float* W = is_q ? W_q : W_k;
    const int xr0 = is_q ? row0 : row0 - BQ * QN;

    const int h0 = (t & 31) * 4;        // 4 h columns
    const int r0 = (t >> 5) * 2;        // 2 rows

    float acc[2][4];
#pragma unroll
    for (int r = 0; r < 2; r++)
#pragma unroll
        for (int c = 0; c < 4; c++) acc[r][c] = 0.f;

    for (int ks = 0; ks < DIN; ks += 32) {
        __syncthreads();
        if (t < 128) {   // x[16 rows][32 k] -> xT[k][row]
            const int r = t >> 3, k4 = (t & 7) * 4;
            float4 xv = *(const float4*)(x + (size_t)(xr0 + r) * DIN + ks + k4);
            xT[k4 + 0][r] = xv.x; xT[k4 + 1][r] = xv.y;
            xT[k4 + 2][r] = xv.z; xT[k4 + 3][r] = xv.w;
        }
#pragma unroll
        for (int u = 0; u < 4; u++) {   // W[128 h][32 k] -> WT[k][h]
            const int h = (t >> 3) + 32 * u, k4 = (t & 7) * 4;
            float4 wv = *(const float4*)(W + (size_t)h * DIN + ks + k4);
            WT[k4 + 0][h] = wv.x; WT[k4 + 1][h] = wv.y;
            WT[k4 + 2][h] = wv.z; WT[k4 + 3][h] = wv.w;
        }
        __syncthreads();
#pragma unroll
        for (int kk = 0; kk < 32; kk++) {
            float2 xv = *(const float2*)&xT[kk][r0];
            float4 wv = *(const float4*)&WT[kk][h0];
            const float xr[2] = {xv.x, xv.y};
            const float wc[4] = {wv.x, wv.y, wv.z, wv.w};
#pragma unroll
            for (int r = 0; r < 2; r++)
#pragma unroll
                for (int c = 0; c < 4; c++)
                    acc[r][c] = __builtin_fmaf(xr[r], wc[c], acc[r][c]);
        }
    }

    if (is_q) {
#pragma unroll
        for (int r = 0; r < 2; r++) {
            float4 o;
            o.x = __builtin_amdgcn_exp2f(C2F * acc[r][0]);
            o.y = __builtin_amdgcn_exp2f(C2F * acc[r][1]);
            o.z = __builtin_amdgcn_exp2f(C2F * acc[r][2]);
            o.w = __builtin_amdgcn_exp2f(C2F * acc[r][3]);
            *(float4*)(Eq + (size_t)(row0 + r0 + r) * HD + h0) = o;
        }
    } else {
        const int krow = row0 - BQ * QN;
        const int b = krow >> 10, k0 = (krow & (KN - 1)) + r0;
        const int h4 = t & 31;                      // = h0/4
#pragma unroll
        for (int r = 0; r < 2; r++) {
            float4 o;
            o.x = __builtin_amdgcn_exp2f(C2F * acc[r][0]);
            o.y = __builtin_amdgcn_exp2f(C2F * acc[r][1]);
            o.z = __builtin_amdgcn_exp2f(C2F * acc[r][2]);
            o.w = __builtin_amdgcn_exp2f(C2F * acc[r][3]);
            *(float4*)(EkT4 + ((size_t)(b * 32 + h4) * KN + k0 + r) * 4) = o;
        }
    }
}

// ---------------------------------------------------------------------------
// Kernel 2: FUSED scores + softmax + attn@V.  Grid = 4b x 128 q-pairs = 512
// blocks, 256 threads, 2 blocks/CU.
// Phase A: thread owns k = c*256+t (c=0..3, chunk skipped if fully masked);
//   2 q-accs; FULL h sum = 32 h-quads (R7 bug: only 16).  Per 4 h:
//   1 dwordx4 Ek load + 8 x {fma,rcp,fma}.  e -> LDS, sums -> shuffle+LDS.
// Phase B: thread = (k-half, q, 16B v-slice); values 1 KB/wave coalesced,
//   e via ds b128 broadcast; cross-half LDS reduce; normalization fused.
// ---------------------------------------------------------------------------
__global__ __launch_bounds__(256, 2) void fused_kernel(const float* __restrict__ Eq,
                                                       const float* __restrict__ EkT4,
                                                       const int* __restrict__ valid_lens,
                                                       const float* __restrict__ w_v,
                                                       const float* __restrict__ values,
                                                       float* __restrict__ out) {
    __shared__ float4 s_pack[HD];       // (w, Eq0, Eq1, -)
    __shared__ float s_e[2][KN];        // unnormalized softmax numerators
    __shared__ float s_red[4][2];
    __shared__ float4 s_bpart[2][2][64];

    const int blk = blockIdx.x;
    const int b = blk & 3;
    const int q0 = (blk >> 2) * 2;
    const int t = threadIdx.x;
    const int valid = valid_lens[b];

    if (t < HD) {
        float w  = w_v[t];
        float p0 = Eq[(size_t)(b * QN + q0) * HD + t];
        float p1 = Eq[(size_t)(b * QN + q0 + 1) * HD + t];
        s_pack[t] = make_float4(w, p0, p1, 0.f);
    }
    __syncthreads();

    // ---- Phase A: scores over ALL 128 h (32 quads) ----
    float rs0 = 0.f, rs1 = 0.f;
    const float4* ekbase = (const float4*)EkT4 + (size_t)(b * 32) * KN;
#pragma unroll
    for (int c = 0; c < 4; c++) {
        const int k = c * 256 + t;
        if (c * 256 < valid) {
            float a0 = 0.f, a1 = 0.f;
            const float4* kcol = ekbase + k;
#pragma unroll 4
            for (int i = 0; i < 32; i++) {
                float4 ek4 = kcol[(size_t)i * KN];
                const float ekv[4] = {ek4.x, ek4.y, ek4.z, ek4.w};
#pragma unroll
                for (int j = 0; j < 4; j++) {
                    float4 p = s_pack[i * 4 + j];
                    a0 = __builtin_fmaf(p.x,
                         __builtin_amdgcn_rcpf(__builtin_fmaf(ekv[j], p.y, 1.0f)), a0);
                    a1 = __builtin_fmaf(p.x,
                         __builtin_amdgcn_rcpf(__builtin_fmaf(ekv[j], p.z, 1.0f)), a1);
                }
            }
            float e0 = (k < valid) ? __builtin_amdgcn_exp2f(NL2E * a0) : 0.f;
            float e1 = (k < valid) ? __builtin_amdgcn_exp2f(NL2E * a1) : 0.f;
            s_e[0][k] = e0;
            s_e[1][k] = e1;
            rs0 += e0;
            rs1 += e1;
        }
    }

    // block-wide row sums (the barrier also publishes s_e for Phase B)
#pragma unroll
    for (int off = 32; off > 0; off >>= 1) {
        rs0 += __shfl_xor(rs0, off, 64);
        rs1 += __shfl_xor(rs1, off, 64);
    }
    const int wvid = t >> 6;
    if ((t & 63) == 0) { s_red[wvid][0] = rs0; s_red[wvid][1] = rs1; }
    __syncthreads();
    const float inv0 = 1.0f / (s_red[0][0] + s_red[1][0] + s_red[2][0] + s_red[3][0]);
    const float inv1 = 1.0f / (s_red[0][1] + s_red[1][1] + s_red[2][1] + s_red[3][1]);

    // ---- Phase B: attn @ values ----
    const int ks = t >> 7;              // k-half
    const int q  = (t >> 6) & 1;        // q-row
    const int l  = t & 63;              // 16B v-slice
    const int beg = ks * 512;
    const int lim = min(valid, beg + 512);
    const float* vp = values + (size_t)b * KN * DIN + l * 4;

    float4 acc = {0.f, 0.f, 0.f, 0.f};
    int k = beg;
    for (; k + 4 <= lim; k += 4) {
        float4 e4 = *(const float4*)&s_e[q][k];      // broadcast b128
        float4 v0 = *(const float4*)(vp + (size_t)k * DIN);
        float4 v1 = *(const float4*)(vp + (size_t)(k + 1) * DIN);
        float4 v2 = *(const float4*)(vp + (size_t)(k + 2) * DIN);
        float4 v3 = *(const float4*)(vp + (size_t)(k + 3) * DIN);
        acc.x += e4.x * v0.x + e4.y * v1.x + e4.z * v2.x + e4.w * v3.x;
        acc.y += e4.x * v0.y + e4.y * v1.y + e4.z * v2.y + e4.w * v3.y;
        acc.z += e4.x * v0.z + e4.y * v1.z + e4.z * v2.z + e4.w * v3.z;
        acc.w += e4.x * v0.w + e4.y * v1.w + e4.z * v2.w + e4.w * v3.w;
    }
    for (; k < lim; k++) {
        float e = s_e[q][k];
        float4 vv = *(const float4*)(vp + (size_t)k * DIN);
        acc.x += e * vv.x; acc.y += e * vv.y;
        acc.z += e * vv.z; acc.w += e * vv.w;
    }
    s_bpart[ks][q][l] = acc;
    __syncthreads();

    if (t < 128) {
        const int q2 = t >> 6, l2 = t & 63;
        float4 a0 = s_bpart[0][q2][l2];
        float4 a1 = s_bpart[1][q2][l2];
        const float inv = q2 ? inv1 : inv0;
        float4 o;
        o.x = (a0.x + a1.x) * inv;
        o.y = (a0.y + a1.y) * inv;
        o.z = (a0.z + a1.z) * inv;
        o.w = (a0.w + a1.w) * inv;
        *(float4*)(out + (size_t)(b * QN + q0 + q2) * DIN + l2 * 4) = o;
    }
}

extern "C" void kernel_launch(void* const* d_in, const int* in_sizes, int n_in,
                              void* d_out, int out_size, void* d_ws, size_t ws_size,
                              hipStream_t stream) {
    const float* queries    = (const float*)d_in[0];
    const float* keys       = (const float*)d_in[1];
    const float* values     = (const float*)d_in[2];
    const int*   valid_lens = (const int*)d_in[3];
    const float* W_q        = (const float*)d_in[4];
    const float* W_k        = (const float*)d_in[5];
    const float* w_v        = (const float*)d_in[6];
    float* out = (float*)d_out;

    float* Eq   = (float*)d_ws;                    // [B*QN][HD]     512 KB
    float* EkT4 = Eq + (size_t)BQ * QN * HD;       // [B][32][KN][4]   2 MB

    proj_kernel<<<(BQ * QN + BQ * KN) / 16, 256, 0, stream>>>(queries, keys, W_q, W_k, Eq, EkT4);
    fused_kernel<<<BQ * (QN / 2), 256, 0, stream>>>(Eq, EkT4, valid_lens, w_v, values, out);
}

// Round 9
// 112.891 us; speedup vs baseline: 1.2512x; 1.2512x over previous
//
#include <hip/hip_runtime.h>
#include <math.h>

#define BQ   4
#define QN   256
#define KN   1024
#define DIN  256     // Q_SIZE == K_SIZE == V_SIZE
#define HD   128     // H

// C2 = 2*log2(e): exp2(C2*x) = e^{2x}
#define C2F   2.8853900817779268f
#define NL2E  (-2.8853900817779268f)

// ---------------------------------------------------------------------------
// Kernel 1: projections as tiled GEMM, outputs in EXP2 DOMAIN (verified R8):
//   Eq  [b*QN+q][h]    = exp2(C2*qp)
//   EkT4[b][h/4][k][4] = exp2(C2*kp)   (4 consecutive h per float4)
// ---------------------------------------------------------------------------
__global__ __launch_bounds__(256, 2) void proj_kernel(const float* __restrict__ queries,
                                                      const float* __restrict__ keys,
                                                      const float* __restrict__ W_q,
                                                      const float* __restrict__ W_k,
                                                      float* __restrict__ Eq,
                                                      float* __restrict__ EkT4) {
    __shared__ float xT[32][18];    // [k][row], 16 rows + pad
    __shared__ float WT[32][136];   // [k][h]

    const int t = threadIdx.x;
    const int row0 = blockIdx.x * 16;
    const bool is_q = row0 < BQ * QN;
    const float* x = is_q ? queries : keys;
    const float* W = is_q ? W_q : W_k;
    const int xr0 = is_q ? row0 : row0 - BQ * QN;

    const int h0 = (t & 31) * 4;        // 4 h columns
    const int r0 = (t >> 5) * 2;        // 2 rows

    float acc[2][4];
#pragma unroll
    for (int r = 0; r < 2; r++)
#pragma unroll
        for (int c = 0; c < 4; c++) acc[r][c] = 0.f;

    for (int ks = 0; ks < DIN; ks += 32) {
        __syncthreads();
        if (t < 128) {   // x[16 rows][32 k] -> xT[k][row]
            const int r = t >> 3, k4 = (t & 7) * 4;
            float4 xv = *(const float4*)(x + (size_t)(xr0 + r) * DIN + ks + k4);
            xT[k4 + 0][r] = xv.x; xT[k4 + 1][r] = xv.y;
            xT[k4 + 2][r] = xv.z; xT[k4 + 3][r] = xv.w;
        }
#pragma unroll
        for (int u = 0; u < 4; u++) {   // W[128 h][32 k] -> WT[k][h]
            const int h = (t >> 3) + 32 * u, k4 = (t & 7) * 4;
            float4 wv = *(const float4*)(W + (size_t)h * DIN + ks + k4);
            WT[k4 + 0][h] = wv.x; WT[k4 + 1][h] = wv.y;
            WT[k4 + 2][h] = wv.z; WT[k4 + 3][h] = wv.w;
        }
        __syncthreads();
#pragma unroll
        for (int kk = 0; kk < 32; kk++) {
            float2 xv = *(const float2*)&xT[kk][r0];
            float4 wv = *(const float4*)&WT[kk][h0];
            const float xr[2] = {xv.x, xv.y};
            const float wc[4] = {wv.x, wv.y, wv.z, wv.w};
#pragma unroll
            for (int r = 0; r < 2; r++)
#pragma unroll
                for (int c = 0; c < 4; c++)
                    acc[r][c] = __builtin_fmaf(xr[r], wc[c], acc[r][c]);
        }
    }

    if (is_q) {
#pragma unroll
        for (int r = 0; r < 2; r++) {
            float4 o;
            o.x = __builtin_amdgcn_exp2f(C2F * acc[r][0]);
            o.y = __builtin_amdgcn_exp2f(C2F * acc[r][1]);
            o.z = __builtin_amdgcn_exp2f(C2F * acc[r][2]);
            o.w = __builtin_amdgcn_exp2f(C2F * acc[r][3]);
            *(float4*)(Eq + (size_t)(row0 + r0 + r) * HD + h0) = o;
        }
    } else {
        const int krow = row0 - BQ * QN;
        const int b = krow >> 10, k0 = (krow & (KN - 1)) + r0;
        const int h4 = t & 31;                      // = h0/4
#pragma unroll
        for (int r = 0; r < 2; r++) {
            float4 o;
            o.x = __builtin_amdgcn_exp2f(C2F * acc[r][0]);
            o.y = __builtin_amdgcn_exp2f(C2F * acc[r][1]);
            o.z = __builtin_amdgcn_exp2f(C2F * acc[r][2]);
            o.w = __builtin_amdgcn_exp2f(C2F * acc[r][3]);
            *(float4*)(EkT4 + ((size_t)(b * 32 + h4) * KN + k0 + r) * 4) = o;
        }
    }
}

// ---------------------------------------------------------------------------
// Kernel 2: scores -> unnormalized e + per-chunk row sums (verified R6).
// Grid = 4b x 32 q-tiles(8) x 8 k-chunks(128) = 1024 blocks (4 blocks/CU).
// ---------------------------------------------------------------------------
__global__ __launch_bounds__(256, 4) void score_kernel(const float* __restrict__ Eq,
                                                       const float* __restrict__ EkT4,
                                                       const int* __restrict__ valid_lens,
                                                       const float* __restrict__ w_v,
                                                       float* __restrict__ attn,
                                                       float* __restrict__ partial) {
    __shared__ float s_w[HD];
    __shared__ float s_pq[HD][8];
    __shared__ float s_part[2][8][128];
    __shared__ float s_red[4][4];

    const int blk = blockIdx.x;
    const int b = blk & 3;
    const int q0 = ((blk >> 2) & 31) * 8;
    const int c = blk >> 7;            // 0..7
    const int t = threadIdx.x;
    const int valid = valid_lens[b];
    float* pp = partial + (size_t)(b * QN + q0) * 8;

    if (c * 128 >= valid) {            // fully masked chunk: attn never read here
        if (t < 8) pp[t * 8 + c] = 0.f;
        return;
    }

    const int kl = t & 127;
    const int hh = t >> 7;
    const int k = c * 128 + kl;

    if (t < HD) s_w[t] = w_v[t];
    {
        const int h = t & 127;
#pragma unroll
        for (int j = 0; j < 4; j++) {
            const int q = (t >> 7) * 4 + j;
            s_pq[h][q] = Eq[(size_t)(b * QN + q0 + q) * HD + h];
        }
    }
    __syncthreads();

    // 4 h per dwordx4: quad index = b*32 + hh*16 + i
    const float4* kcol = (const float4*)EkT4 + ((size_t)(b * 32 + hh * 16) * KN + k);
    float acc[8] = {0.f, 0.f, 0.f, 0.f, 0.f, 0.f, 0.f, 0.f};

#pragma unroll 4
    for (int i = 0; i < 16; i++) {
        float4 ek4 = kcol[(size_t)i * KN];
        const int hb = hh * 64 + i * 4;
        const float ekv[4] = {ek4.x, ek4.y, ek4.z, ek4.w};
#pragma unroll
        for (int j = 0; j < 4; j++) {
            const float ek = ekv[j];
            const float w = s_w[hb + j];
            float4 p0 = *(const float4*)&s_pq[hb + j][0];
            float4 p1 = *(const float4*)&s_pq[hb + j][4];
            acc[0] = __builtin_fmaf(w, __builtin_amdgcn_rcpf(__builtin_fmaf(ek, p0.x, 1.0f)), acc[0]);
            acc[1] = __builtin_fmaf(w, __builtin_amdgcn_rcpf(__builtin_fmaf(ek, p0.y, 1.0f)), acc[1]);
            acc[2] = __builtin_fmaf(w, __builtin_amdgcn_rcpf(__builtin_fmaf(ek, p0.z, 1.0f)), acc[2]);
            acc[3] = __builtin_fmaf(w, __builtin_amdgcn_rcpf(__builtin_fmaf(ek, p0.w, 1.0f)), acc[3]);
            acc[4] = __builtin_fmaf(w, __builtin_amdgcn_rcpf(__builtin_fmaf(ek, p1.x, 1.0f)), acc[4]);
            acc[5] = __builtin_fmaf(w, __builtin_amdgcn_rcpf(__builtin_fmaf(ek, p1.y, 1.0f)), acc[5]);
            acc[6] = __builtin_fmaf(w, __builtin_amdgcn_rcpf(__builtin_fmaf(ek, p1.z, 1.0f)), acc[6]);
            acc[7] = __builtin_fmaf(w, __builtin_amdgcn_rcpf(__builtin_fmaf(ek, p1.w, 1.0f)), acc[7]);
        }
    }

#pragma unroll
    for (int q = 0; q < 8; q++) s_part[hh][q][kl] = acc[q];
    __syncthreads();

    const int qb = (t >> 7) * 4;
    float* arow = attn + (size_t)(b * QN + q0 + qb) * KN + k;
    float psum[4];
#pragma unroll
    for (int j = 0; j < 4; j++) {
        const int q = qb + j;
        float tot = s_part[0][q][kl] + s_part[1][q][kl];
        float e = (k < valid) ? __builtin_amdgcn_exp2f(NL2E * tot) : 0.f;
        arow[(size_t)j * KN] = e;
#pragma unroll
        for (int off = 32; off > 0; off >>= 1) e += __shfl_xor(e, off, 64);
        psum[j] = e;
    }
    const int wv = t >> 6;
    if ((t & 63) == 0) {
#pragma unroll
        for (int j = 0; j < 4; j++) s_red[wv][j] = psum[j];
    }
    __syncthreads();
    if (t < 8) {
        const int q = t;
        float s = (q < 4) ? (s_red[0][q] + s_red[1][q])
                          : (s_red[2][q - 4] + s_red[3][q - 4]);
        pp[q * 8 + c] = s;
    }
}

// ---------------------------------------------------------------------------
// Kernel 3: out = normalize(e) @ values as a REGISTER-PREFETCHED TILED GEMM.
// Grid = 4b x 8 q-tiles x 8 v-tiles (32x32 output tiles) = 256 blocks.
// Per k-tile (32 k): stage attn^T and V in LDS; wave ks owns k-slice
// [ks*8, ks*8+8); thread = 4q x 4v = 16 acc (16 fma per 2 ds_read_b128 ->
// VALU-bound); next tile's fragments prefetched into registers BEFORE the
// compute so global latency hides behind the fma stream.  k-slices reduced
// through LDS; normalization (1/rowsum from `partial`) fused in epilogue.
// k-loop stops at ceil(valid/32) tiles; score wrote e=0 for k>=valid there.
// ---------------------------------------------------------------------------
__global__ __launch_bounds__(256, 2) void av_kernel(const float* __restrict__ attn,
                                                    const float* __restrict__ partial,
                                                    const float* __restrict__ values,
                                                    const int* __restrict__ valid_lens,
                                                    float* __restrict__ out) {
    __shared__ float s_aT[32][36];      // [kk][q]
    __shared__ float s_v[32][36];       // [kk][v]
    __shared__ float s_red[4][32][36];  // per-k-slice partials
    __shared__ float s_inv[32];

    const int blk = blockIdx.x;
    const int b = blk & 3;
    const int qt = (blk >> 2) & 7;
    const int vt = blk >> 5;
    const int t = threadIdx.x;
    const int q0 = qt * 32, v0 = vt * 32;
    const int valid = valid_lens[b];
    const int T = (valid + 31) >> 5;    // k-tiles (valid >= 1 so T >= 1)

    if (t < 32) {
        const float* pr = partial + (size_t)(b * QN + q0 + t) * 8;
        float4 pA = *(const float4*)pr;
        float4 pB = *(const float4*)(pr + 4);
        s_inv[t] = 1.0f / (pA.x + pA.y + pA.z + pA.w + pB.x + pB.y + pB.z + pB.w);
    }

    // staging: thread loads attn[q0+sr][kt+sc..+3] and V[kt+sr][v0+sc..+3]
    const int sr = t >> 3, sc = (t & 7) * 4;
    const float* abase = attn + (size_t)(b * QN + q0 + sr) * KN + sc;
    const float* vbase = values + ((size_t)b * KN + sr) * DIN + v0 + sc;

    const int vh = t & 7, qh = (t >> 3) & 7, ks = t >> 6;   // wave = k-slice

    float acc[4][4];
#pragma unroll
    for (int r = 0; r < 4; r++)
#pragma unroll
        for (int c = 0; c < 4; c++) acc[r][c] = 0.f;

    float4 ra = *(const float4*)abase;      // prefetch tile 0
    float4 rv = *(const float4*)vbase;

    for (int tile = 0; tile < T; tile++) {
        __syncthreads();
        s_aT[sc + 0][sr] = ra.x;            // attn transposed -> [kk][q]
        s_aT[sc + 1][sr] = ra.y;
        s_aT[sc + 2][sr] = ra.z;
        s_aT[sc + 3][sr] = ra.w;
        *(float4*)&s_v[sr][sc] = rv;
        __syncthreads();
        if (tile + 1 < T) {                 // issue next tile's loads now;
            ra = *(const float4*)(abase + (tile + 1) * 32);
            rv = *(const float4*)(vbase + (size_t)(tile + 1) * 32 * DIN);
        }                                   // ...they drain during compute
#pragma unroll
        for (int i = 0; i < 8; i++) {
            const int kk = ks * 8 + i;
            float4 aq = *(const float4*)&s_aT[kk][qh * 4];
            float4 vv = *(const float4*)&s_v[kk][vh * 4];
            const float ar[4] = {aq.x, aq.y, aq.z, aq.w};
            const float vc[4] = {vv.x, vv.y, vv.z, vv.w};
#pragma unroll
            for (int r = 0; r < 4; r++)
#pragma unroll
                for (int c = 0; c < 4; c++)
                    acc[r][c] = __builtin_fmaf(ar[r], vc[c], acc[r][c]);
        }
    }

#pragma unroll
    for (int r = 0; r < 4; r++)
        *(float4*)&s_red[ks][qh * 4 + r][vh * 4] =
            make_float4(acc[r][0], acc[r][1], acc[r][2], acc[r][3]);
    __syncthreads();

    {   // epilogue: sum 4 k-slices, normalize, coalesced float4 store
        const int q = t >> 3, v4 = (t & 7) * 4;
        float4 r0 = *(const float4*)&s_red[0][q][v4];
        float4 r1 = *(const float4*)&s_red[1][q][v4];
        float4 r2 = *(const float4*)&s_red[2][q][v4];
        float4 r3 = *(const float4*)&s_red[3][q][v4];
        const float inv = s_inv[q];
        float4 o;
        o.x = (r0.x + r1.x + r2.x + r3.x) * inv;
        o.y = (r0.y + r1.y + r2.y + r3.y) * inv;
        o.z = (r0.z + r1.z + r2.z + r3.z) * inv;
        o.w = (r0.w + r1.w + r2.w + r3.w) * inv;
        *(float4*)(out + (size_t)(b * QN + q0 + q) * DIN + v0 + v4) = o;
    }
}

extern "C" void kernel_launch(void* const* d_in, const int* in_sizes, int n_in,
                              void* d_out, int out_size, void* d_ws, size_t ws_size,
                              hipStream_t stream) {
    const float* queries    = (const float*)d_in[0];
    const float* keys       = (const float*)d_in[1];
    const float* values     = (const float*)d_in[2];
    const int*   valid_lens = (const int*)d_in[3];
    const float* W_q        = (const float*)d_in[4];
    const float* W_k        = (const float*)d_in[5];
    const float* w_v        = (const float*)d_in[6];
    float* out = (float*)d_out;

    float* Eq      = (float*)d_ws;                    // [B*QN][HD]     512 KB
    float* EkT4    = Eq + (size_t)BQ * QN * HD;       // [B][32][KN][4]   2 MB
    float* attn    = EkT4 + (size_t)BQ * HD * KN;     // [B*QN][KN]       4 MB
    float* partial = attn + (size_t)BQ * QN * KN;     // [B*QN][8]       32 KB

    proj_kernel<<<(BQ * QN + BQ * KN) / 16, 256, 0, stream>>>(queries, keys, W_q, W_k, Eq, EkT4);
    score_kernel<<<BQ * (QN / 8) * 8, 256, 0, stream>>>(Eq, EkT4, valid_lens, w_v, attn, partial);
    av_kernel<<<BQ * 8 * 8, 256, 0, stream>>>(attn, partial, values, valid_lens, out);
}